// Round 4
// baseline (444.612 us; speedup 1.0000x reference)
//
#include <hip/hip_runtime.h>

#define DEV_INLINE __device__ __forceinline__

constexpr int NF = 26;   // input features
constexpr int H1 = 24;   // layer-1 hidden
constexpr int H2 = 8;    // layer-2 hidden
constexpr int T  = 5;    // sequence length

DEV_INLINE float fast_rcp(float x) { return __builtin_amdgcn_rcpf(x); }
// sigmoid(x) = 1/(1+exp(-x))
DEV_INLINE float fast_sigmoid(float x) { return fast_rcp(1.0f + __expf(-x)); }
// tanh(x) = 2/(1+exp(-2x)) - 1
DEV_INLINE float fast_tanh(float x) {
    return fmaf(2.0f, fast_rcp(1.0f + __expf(-2.0f * x)), -1.0f);
}

// LDS weight layout: gate-interleaved float4 so one ds_read_b128 (uniform
// address -> broadcast, conflict-free) feeds the 4 gate FMA chains of BOTH
// batch elements handled by the thread (8 FMAs per load).
// Total LDS: (624+576+192+64+24+8)*16B = 23808 B per block.

__global__ __launch_bounds__(256, 2) void lstm2_fused(
    const float* __restrict__ x,
    const float* __restrict__ w_ih1, const float* __restrict__ w_hh1,
    const float* __restrict__ b_ih1, const float* __restrict__ b_hh1,
    const float* __restrict__ w_ih2, const float* __restrict__ w_hh2,
    const float* __restrict__ b_ih2, const float* __restrict__ b_hh2,
    float* __restrict__ out, int batch)
{
    __shared__ float4 s_wih1[H1 * NF];
    __shared__ float4 s_whh1[H1 * H1];
    __shared__ float4 s_wih2[H2 * H1];
    __shared__ float4 s_whh2[H2 * H2];
    __shared__ float4 s_b1[H1];
    __shared__ float4 s_b2[H2];

    const int tid = threadIdx.x;

    // ---- cooperative repack: global (gate-major rows) -> LDS (gate-interleaved) ----
    {
        float* d = reinterpret_cast<float*>(s_wih1);
        for (int e = tid; e < H1 * NF * 4; e += 256) {
            int g = e & 3, r = e >> 2, i = r % NF, j = r / NF;
            d[e] = w_ih1[(g * H1 + j) * NF + i];
        }
        d = reinterpret_cast<float*>(s_whh1);
        for (int e = tid; e < H1 * H1 * 4; e += 256) {
            int g = e & 3, r = e >> 2, k = r % H1, j = r / H1;
            d[e] = w_hh1[(g * H1 + j) * H1 + k];
        }
        d = reinterpret_cast<float*>(s_wih2);
        for (int e = tid; e < H2 * H1 * 4; e += 256) {
            int g = e & 3, r = e >> 2, k = r % H1, j = r / H1;
            d[e] = w_ih2[(g * H2 + j) * H1 + k];
        }
        d = reinterpret_cast<float*>(s_whh2);
        for (int e = tid; e < H2 * H2 * 4; e += 256) {
            int g = e & 3, r = e >> 2, k = r % H2, j = r / H2;
            d[e] = w_hh2[(g * H2 + j) * H2 + k];
        }
        d = reinterpret_cast<float*>(s_b1);
        if (tid < H1 * 4) {
            int g = tid & 3, j = tid >> 2;
            d[tid] = b_ih1[g * H1 + j] + b_hh1[g * H1 + j];
        }
        d = reinterpret_cast<float*>(s_b2);
        if (tid < H2 * 4) {
            int g = tid & 3, j = tid >> 2;
            d[tid] = b_ih2[g * H2 + j] + b_hh2[g * H2 + j];
        }
    }
    __syncthreads();

    // two batch elements per thread: [base+tid] and [base+256+tid] (both coalesced)
    const int base = blockIdx.x * 512;
    const int b0 = base + tid;
    const int b1 = base + 256 + tid;
    const bool v0 = (b0 < batch);
    const bool v1 = (b1 < batch);
    const int i0 = v0 ? b0 : (batch - 1);   // clamp loads, predicate stores
    const int i1 = v1 ? b1 : (batch - 1);
    const float* __restrict__ xb0 = x + (size_t)i0 * (T * NF);
    const float* __restrict__ xb1 = x + (size_t)i1 * (T * NF);

    float h10[H1], c10[H1], h11[H1], c11[H1];
    float h20[H2], c20[H2], h21[H2], c21[H2];
    #pragma unroll
    for (int j = 0; j < H1; ++j) { h10[j] = 0.f; c10[j] = 0.f; h11[j] = 0.f; c11[j] = 0.f; }
    #pragma unroll
    for (int j = 0; j < H2; ++j) { h20[j] = 0.f; c20[j] = 0.f; h21[j] = 0.f; c21[j] = 0.f; }

    #pragma unroll 1   // keep scheduling regions small (one timestep)
    for (int t = 0; t < T; ++t) {
        // ---- load x_t for both elements (26 floats each, 8B-aligned) ----
        float xt0[NF], xt1[NF];
        {
            const float2* xp0 = reinterpret_cast<const float2*>(xb0 + t * NF);
            const float2* xp1 = reinterpret_cast<const float2*>(xb1 + t * NF);
            #pragma unroll
            for (int i = 0; i < NF / 2; ++i) {
                float2 a = xp0[i]; xt0[2*i] = a.x; xt0[2*i+1] = a.y;
                float2 b = xp1[i]; xt1[2*i] = b.x; xt1[2*i+1] = b.y;
            }
        }

        // ---- layer 1 ----
        float h1n0[H1], h1n1[H1];
        #pragma unroll
        for (int j = 0; j < H1; ++j) {
            float4 bv = s_b1[j];
            float a0i = bv.x, a0f = bv.y, a0g = bv.z, a0o = bv.w;
            float a1i = bv.x, a1f = bv.y, a1g = bv.z, a1o = bv.w;
            #pragma unroll
            for (int i = 0; i < NF; ++i) {
                float4 w = s_wih1[j * NF + i];     // ds_read_b128 broadcast, 8 FMAs
                const float x0 = xt0[i], x1 = xt1[i];
                a0i = fmaf(w.x, x0, a0i);  a1i = fmaf(w.x, x1, a1i);
                a0f = fmaf(w.y, x0, a0f);  a1f = fmaf(w.y, x1, a1f);
                a0g = fmaf(w.z, x0, a0g);  a1g = fmaf(w.z, x1, a1g);
                a0o = fmaf(w.w, x0, a0o);  a1o = fmaf(w.w, x1, a1o);
            }
            if (t > 0) {  // h == 0 at t==0: recurrent part contributes exactly 0
                #pragma unroll
                for (int k = 0; k < H1; ++k) {
                    float4 w = s_whh1[j * H1 + k];
                    const float p0 = h10[k], p1 = h11[k];
                    a0i = fmaf(w.x, p0, a0i);  a1i = fmaf(w.x, p1, a1i);
                    a0f = fmaf(w.y, p0, a0f);  a1f = fmaf(w.y, p1, a1f);
                    a0g = fmaf(w.z, p0, a0g);  a1g = fmaf(w.z, p1, a1g);
                    a0o = fmaf(w.w, p0, a0o);  a1o = fmaf(w.w, p1, a1o);
                }
            }
            {
                const float ig = fast_sigmoid(a0i), fg = fast_sigmoid(a0f);
                const float gg = fast_tanh(a0g),    og = fast_sigmoid(a0o);
                const float c  = fmaf(fg, c10[j], ig * gg);
                c10[j]  = c;
                h1n0[j] = og * fast_tanh(c);
            }
            {
                const float ig = fast_sigmoid(a1i), fg = fast_sigmoid(a1f);
                const float gg = fast_tanh(a1g),    og = fast_sigmoid(a1o);
                const float c  = fmaf(fg, c11[j], ig * gg);
                c11[j]  = c;
                h1n1[j] = og * fast_tanh(c);
            }
            __builtin_amdgcn_sched_barrier(0);  // proven pressure control (R1 vs R3)
        }
        #pragma unroll
        for (int j = 0; j < H1; ++j) { h10[j] = h1n0[j]; h11[j] = h1n1[j]; }

        // ---- layer 2 (consumes h1 of this timestep) ----
        float h2n0[H2], h2n1[H2];
        #pragma unroll
        for (int j = 0; j < H2; ++j) {
            float4 bv = s_b2[j];
            float a0i = bv.x, a0f = bv.y, a0g = bv.z, a0o = bv.w;
            float a1i = bv.x, a1f = bv.y, a1g = bv.z, a1o = bv.w;
            #pragma unroll
            for (int k = 0; k < H1; ++k) {
                float4 w = s_wih2[j * H1 + k];
                const float p0 = h10[k], p1 = h11[k];
                a0i = fmaf(w.x, p0, a0i);  a1i = fmaf(w.x, p1, a1i);
                a0f = fmaf(w.y, p0, a0f);  a1f = fmaf(w.y, p1, a1f);
                a0g = fmaf(w.z, p0, a0g);  a1g = fmaf(w.z, p1, a1g);
                a0o = fmaf(w.w, p0, a0o);  a1o = fmaf(w.w, p1, a1o);
            }
            if (t > 0) {
                #pragma unroll
                for (int k = 0; k < H2; ++k) {
                    float4 w = s_whh2[j * H2 + k];
                    const float p0 = h20[k], p1 = h21[k];
                    a0i = fmaf(w.x, p0, a0i);  a1i = fmaf(w.x, p1, a1i);
                    a0f = fmaf(w.y, p0, a0f);  a1f = fmaf(w.y, p1, a1f);
                    a0g = fmaf(w.z, p0, a0g);  a1g = fmaf(w.z, p1, a1g);
                    a0o = fmaf(w.w, p0, a0o);  a1o = fmaf(w.w, p1, a1o);
                }
            }
            {
                const float ig = fast_sigmoid(a0i), fg = fast_sigmoid(a0f);
                const float gg = fast_tanh(a0g),    og = fast_sigmoid(a0o);
                const float c  = fmaf(fg, c20[j], ig * gg);
                c20[j]  = c;
                h2n0[j] = og * fast_tanh(c);
            }
            {
                const float ig = fast_sigmoid(a1i), fg = fast_sigmoid(a1f);
                const float gg = fast_tanh(a1g),    og = fast_sigmoid(a1o);
                const float c  = fmaf(fg, c21[j], ig * gg);
                c21[j]  = c;
                h2n1[j] = og * fast_tanh(c);
            }
            __builtin_amdgcn_sched_barrier(0);
        }
        #pragma unroll
        for (int j = 0; j < H2; ++j) { h20[j] = h2n0[j]; h21[j] = h2n1[j]; }
    }

    // ---- write final h2: 32 contiguous bytes per element, coalesced ----
    if (v0) {
        float4* op = reinterpret_cast<float4*>(out + (size_t)b0 * H2);
        op[0] = make_float4(h20[0], h20[1], h20[2], h20[3]);
        op[1] = make_float4(h20[4], h20[5], h20[6], h20[7]);
    }
    if (v1) {
        float4* op = reinterpret_cast<float4*>(out + (size_t)b1 * H2);
        op[0] = make_float4(h21[0], h21[1], h21[2], h21[3]);
        op[1] = make_float4(h21[4], h21[5], h21[6], h21[7]);
    }
}

extern "C" void kernel_launch(void* const* d_in, const int* in_sizes, int n_in,
                              void* d_out, int out_size, void* d_ws, size_t ws_size,
                              hipStream_t stream)
{
    const float* x     = (const float*)d_in[0];
    const float* w_ih1 = (const float*)d_in[1];
    const float* w_hh1 = (const float*)d_in[2];
    const float* b_ih1 = (const float*)d_in[3];
    const float* b_hh1 = (const float*)d_in[4];
    const float* w_ih2 = (const float*)d_in[5];
    const float* w_hh2 = (const float*)d_in[6];
    const float* b_ih2 = (const float*)d_in[7];
    const float* b_hh2 = (const float*)d_in[8];
    float* out = (float*)d_out;

    const int batch = in_sizes[0] / (T * NF);
    const int block = 256;
    const int elems_per_block = block * 2;
    const int grid  = (batch + elems_per_block - 1) / elems_per_block;
    lstm2_fused<<<grid, block, 0, stream>>>(x, w_ih1, w_hh1, b_ih1, b_hh1,
                                            w_ih2, w_hh2, b_ih2, b_hh2,
                                            out, batch);
}

// Round 5
// 358.965 us; speedup vs baseline: 1.2386x; 1.2386x over previous
//
#include <hip/hip_runtime.h>

#define DEV_INLINE __device__ __forceinline__

constexpr int NF = 26;   // input features
constexpr int H1 = 24;   // layer-1 hidden
constexpr int H2 = 8;    // layer-2 hidden
constexpr int T  = 5;    // sequence length

DEV_INLINE float fast_rcp(float x) { return __builtin_amdgcn_rcpf(x); }
// sigmoid(x) = 1/(1+exp(-x))
DEV_INLINE float fast_sigmoid(float x) { return fast_rcp(1.0f + __expf(-x)); }
// tanh(x) = 2/(1+exp(-2x)) - 1
DEV_INLINE float fast_tanh(float x) {
    return fmaf(2.0f, fast_rcp(1.0f + __expf(-2.0f * x)), -1.0f);
}

// LDS weight layout: 4 gate weights (i,f,g,o) packed as fp16 into one uint2
// -> single ds_read_b64 uniform broadcast (512B return vs 1KB for b128).
// Consumed as fmaf((float)f16, x, acc): LLVM folds fpext+fma -> v_fma_mix_f32
// (f16 operand, fp32 accumulate). Biases stay fp32 (float4).
// LDS: (624+576+192+64)*8B + (24+8)*16B = 12160 B per block.

typedef __attribute__((ext_vector_type(4))) _Float16 half4;
union WPack { uint2 u; half4 h; };

__global__ __launch_bounds__(256) void lstm2_fused(
    const float* __restrict__ x,
    const float* __restrict__ w_ih1, const float* __restrict__ w_hh1,
    const float* __restrict__ b_ih1, const float* __restrict__ b_hh1,
    const float* __restrict__ w_ih2, const float* __restrict__ w_hh2,
    const float* __restrict__ b_ih2, const float* __restrict__ b_hh2,
    float* __restrict__ out, int batch)
{
    __shared__ uint2 s_wih1[H1 * NF];
    __shared__ uint2 s_whh1[H1 * H1];
    __shared__ uint2 s_wih2[H2 * H1];
    __shared__ uint2 s_whh2[H2 * H2];
    __shared__ float4 s_b1[H1];
    __shared__ float4 s_b2[H2];

    const int tid = threadIdx.x;

    // ---- cooperative repack: global f32 (gate-major rows) -> LDS packed f16 ----
    for (int e = tid; e < H1 * NF; e += 256) {
        int i = e % NF, j = e / NF;
        WPack w;
        w.h[0] = (_Float16)w_ih1[(0 * H1 + j) * NF + i];
        w.h[1] = (_Float16)w_ih1[(1 * H1 + j) * NF + i];
        w.h[2] = (_Float16)w_ih1[(2 * H1 + j) * NF + i];
        w.h[3] = (_Float16)w_ih1[(3 * H1 + j) * NF + i];
        s_wih1[e] = w.u;
    }
    for (int e = tid; e < H1 * H1; e += 256) {
        int k = e % H1, j = e / H1;
        WPack w;
        w.h[0] = (_Float16)w_hh1[(0 * H1 + j) * H1 + k];
        w.h[1] = (_Float16)w_hh1[(1 * H1 + j) * H1 + k];
        w.h[2] = (_Float16)w_hh1[(2 * H1 + j) * H1 + k];
        w.h[3] = (_Float16)w_hh1[(3 * H1 + j) * H1 + k];
        s_whh1[e] = w.u;
    }
    for (int e = tid; e < H2 * H1; e += 256) {
        int k = e % H1, j = e / H1;
        WPack w;
        w.h[0] = (_Float16)w_ih2[(0 * H2 + j) * H1 + k];
        w.h[1] = (_Float16)w_ih2[(1 * H2 + j) * H1 + k];
        w.h[2] = (_Float16)w_ih2[(2 * H2 + j) * H1 + k];
        w.h[3] = (_Float16)w_ih2[(3 * H2 + j) * H1 + k];
        s_wih2[e] = w.u;
    }
    for (int e = tid; e < H2 * H2; e += 256) {
        int k = e % H2, j = e / H2;
        WPack w;
        w.h[0] = (_Float16)w_hh2[(0 * H2 + j) * H2 + k];
        w.h[1] = (_Float16)w_hh2[(1 * H2 + j) * H2 + k];
        w.h[2] = (_Float16)w_hh2[(2 * H2 + j) * H2 + k];
        w.h[3] = (_Float16)w_hh2[(3 * H2 + j) * H2 + k];
        s_whh2[e] = w.u;
    }
    {
        float* d = reinterpret_cast<float*>(s_b1);
        if (tid < H1 * 4) {
            int g = tid & 3, j = tid >> 2;
            d[tid] = b_ih1[g * H1 + j] + b_hh1[g * H1 + j];
        }
        d = reinterpret_cast<float*>(s_b2);
        if (tid < H2 * 4) {
            int g = tid & 3, j = tid >> 2;
            d[tid] = b_ih2[g * H2 + j] + b_hh2[g * H2 + j];
        }
    }
    __syncthreads();

    const int b = blockIdx.x * blockDim.x + tid;
    if (b >= batch) return;
    const float* __restrict__ xb = x + (size_t)b * (T * NF);

    float h1[H1], c1[H1];
    float h2v[H2], c2[H2];
    #pragma unroll
    for (int j = 0; j < H1; ++j) { h1[j] = 0.0f; c1[j] = 0.0f; }
    #pragma unroll
    for (int j = 0; j < H2; ++j) { h2v[j] = 0.0f; c2[j] = 0.0f; }

    #pragma unroll 1   // keep scheduling regions small (one timestep)
    for (int t = 0; t < T; ++t) {
        // ---- load x_t (26 floats, 8B-aligned) ----
        float xt[NF];
        const float2* xp = reinterpret_cast<const float2*>(xb + t * NF);
        #pragma unroll
        for (int i = 0; i < NF / 2; ++i) {
            float2 v = xp[i];
            xt[2 * i] = v.x;
            xt[2 * i + 1] = v.y;
        }

        // ---- layer 1 ----
        float h1n[H1];
        #pragma unroll
        for (int j = 0; j < H1; ++j) {
            float4 bv = s_b1[j];
            float ai = bv.x, af = bv.y, ag = bv.z, ao = bv.w;
            #pragma unroll
            for (int i = 0; i < NF; ++i) {
                WPack w; w.u = s_wih1[j * NF + i];   // ds_read_b64 broadcast
                const float xi = xt[i];
                ai = fmaf((float)w.h[0], xi, ai);    // -> v_fma_mix_f32
                af = fmaf((float)w.h[1], xi, af);
                ag = fmaf((float)w.h[2], xi, ag);
                ao = fmaf((float)w.h[3], xi, ao);
            }
            if (t > 0) {  // h1 == 0 at t==0: recurrent part contributes exactly 0
                #pragma unroll
                for (int k = 0; k < H1; ++k) {
                    WPack w; w.u = s_whh1[j * H1 + k];
                    const float hk = h1[k];
                    ai = fmaf((float)w.h[0], hk, ai);
                    af = fmaf((float)w.h[1], hk, af);
                    ag = fmaf((float)w.h[2], hk, ag);
                    ao = fmaf((float)w.h[3], hk, ao);
                }
            }
            const float ig = fast_sigmoid(ai);
            const float fg = fast_sigmoid(af);
            const float gg = fast_tanh(ag);
            const float og = fast_sigmoid(ao);
            const float c  = fmaf(fg, c1[j], ig * gg);  // c1==0 at t==0: exact
            c1[j]  = c;
            h1n[j] = og * fast_tanh(c);
            __builtin_amdgcn_sched_barrier(0);  // proven pressure control (R1/R3/R4)
        }
        #pragma unroll
        for (int j = 0; j < H1; ++j) h1[j] = h1n[j];

        // ---- layer 2 (consumes h1 of this timestep) ----
        float h2n[H2];
        #pragma unroll
        for (int j = 0; j < H2; ++j) {
            float4 bv = s_b2[j];
            float ai = bv.x, af = bv.y, ag = bv.z, ao = bv.w;
            #pragma unroll
            for (int k = 0; k < H1; ++k) {
                WPack w; w.u = s_wih2[j * H1 + k];
                const float hk = h1[k];
                ai = fmaf((float)w.h[0], hk, ai);
                af = fmaf((float)w.h[1], hk, af);
                ag = fmaf((float)w.h[2], hk, ag);
                ao = fmaf((float)w.h[3], hk, ao);
            }
            if (t > 0) {
                #pragma unroll
                for (int k = 0; k < H2; ++k) {
                    WPack w; w.u = s_whh2[j * H2 + k];
                    const float hk = h2v[k];
                    ai = fmaf((float)w.h[0], hk, ai);
                    af = fmaf((float)w.h[1], hk, af);
                    ag = fmaf((float)w.h[2], hk, ag);
                    ao = fmaf((float)w.h[3], hk, ao);
                }
            }
            const float ig = fast_sigmoid(ai);
            const float fg = fast_sigmoid(af);
            const float gg = fast_tanh(ag);
            const float og = fast_sigmoid(ao);
            const float c  = fmaf(fg, c2[j], ig * gg);
            c2[j]  = c;
            h2n[j] = og * fast_tanh(c);
            __builtin_amdgcn_sched_barrier(0);
        }
        #pragma unroll
        for (int j = 0; j < H2; ++j) h2v[j] = h2n[j];
    }

    // ---- write final h2: 32 contiguous bytes per thread, coalesced ----
    float4* op = reinterpret_cast<float4*>(out + (size_t)b * H2);
    op[0] = make_float4(h2v[0], h2v[1], h2v[2], h2v[3]);
    op[1] = make_float4(h2v[4], h2v[5], h2v[6], h2v[7]);
}

extern "C" void kernel_launch(void* const* d_in, const int* in_sizes, int n_in,
                              void* d_out, int out_size, void* d_ws, size_t ws_size,
                              hipStream_t stream)
{
    const float* x     = (const float*)d_in[0];
    const float* w_ih1 = (const float*)d_in[1];
    const float* w_hh1 = (const float*)d_in[2];
    const float* b_ih1 = (const float*)d_in[3];
    const float* b_hh1 = (const float*)d_in[4];
    const float* w_ih2 = (const float*)d_in[5];
    const float* w_hh2 = (const float*)d_in[6];
    const float* b_ih2 = (const float*)d_in[7];
    const float* b_hh2 = (const float*)d_in[8];
    float* out = (float*)d_out;

    const int batch = in_sizes[0] / (T * NF);
    const int block = 256;
    const int grid  = (batch + block - 1) / block;
    lstm2_fused<<<grid, block, 0, stream>>>(x, w_ih1, w_hh1, b_ih1, b_hh1,
                                            w_ih2, w_hh2, b_ih2, b_hh2,
                                            out, batch);
}

// Round 8
// 226.889 us; speedup vs baseline: 1.9596x; 1.5821x over previous
//
#include <hip/hip_runtime.h>

#define DEV_INLINE __device__ __forceinline__

constexpr int NF = 26;   // input features
constexpr int H1 = 24;   // layer-1 hidden
constexpr int H2 = 8;    // layer-2 hidden
constexpr int T  = 5;    // sequence length
constexpr int NP = NF / 2;  // 13 x fp16-pairs
constexpr int P1 = H1 / 2;  // 12 h1 pairs
constexpr int P2 = H2 / 2;  // 4  h2 pairs

typedef __attribute__((ext_vector_type(2))) _Float16 half2v;
typedef __attribute__((ext_vector_type(2))) __fp16   fp16x2;
union HP { uint u; half2v h; fp16x2 p; };

DEV_INLINE float fast_rcp(float x) { return __builtin_amdgcn_rcpf(x); }
DEV_INLINE float fast_sigmoid(float x) { return fast_rcp(1.0f + __expf(-x)); }
DEV_INLINE float fast_tanh(float x) {
    return fmaf(2.0f, fast_rcp(1.0f + __expf(-2.0f * x)), -1.0f);
}
// v_dot2_f32_f16: 2 fp16 MACs, fp32 accumulate, one instruction
DEV_INLINE float fdot2(uint w, uint v, float acc) {
    HP a, b; a.u = w; b.u = v;
    return __builtin_amdgcn_fdot2(a.h, b.h, acc, false);
}
DEV_INLINE uint packh2_acc(float a, float b) {  // RTN pack (staging, accurate)
    HP p; p.h[0] = (_Float16)a; p.h[1] = (_Float16)b; return p.u;
}
DEV_INLINE uint pkrtz(float a, float b) {       // 1-instr v_cvt_pkrtz (hot loop)
    HP p; p.p = __builtin_amdgcn_cvt_pkrtz(a, b); return p.u;
}
// LSTM cell: gates (i,f,g,o) in float4, updates c in place, returns h
DEV_INLINE float cellh(float4 a, float& cst) {
    const float ig = fast_sigmoid(a.x), fg = fast_sigmoid(a.y);
    const float gg = fast_tanh(a.z),    og = fast_sigmoid(a.w);
    const float c  = fmaf(fg, cst, ig * gg);
    cst = c;
    return og * fast_tanh(c);
}
// One K-step: 4-gate dot2 update of accumulator from packed weight quad + operand pair
DEV_INLINE void dot4(float4& a, const uint4 w, const uint v) {
    a.x = fdot2(w.x, v, a.x);
    a.y = fdot2(w.y, v, a.y);
    a.z = fdot2(w.z, v, a.z);
    a.w = fdot2(w.w, v, a.w);
}

// LDS: weights as fp16 gate-packed pairs. s_w[row][pair] = uint4 holding the
// (i,f,g,o) gate weights for 2 consecutive k/i indices. One ds_read_b128
// (uniform broadcast) feeds 8 dot2 = 16 MACs across the thread's 2 elements.
// Total: (312+288+96+32)*16 + (24+8)*16 = 12160 B per block.

__global__ __launch_bounds__(256, 1) void lstm2_fused(
    const float* __restrict__ x,
    const float* __restrict__ w_ih1, const float* __restrict__ w_hh1,
    const float* __restrict__ b_ih1, const float* __restrict__ b_hh1,
    const float* __restrict__ w_ih2, const float* __restrict__ w_hh2,
    const float* __restrict__ b_ih2, const float* __restrict__ b_hh2,
    float* __restrict__ out, int batch)
{
    __shared__ uint4 s_wih1[H1 * NP];
    __shared__ uint4 s_whh1[H1 * P1];
    __shared__ uint4 s_wih2[H2 * P1];
    __shared__ uint4 s_whh2[H2 * P2];
    __shared__ float4 s_b1[H1];
    __shared__ float4 s_b2[H2];

    const int tid = threadIdx.x;

    // ---- cooperative repack: global f32 (gate-major rows) -> LDS fp16 pairs ----
    for (int e = tid; e < H1 * NP; e += 256) {
        int ip = e % NP, j = e / NP;
        uint4 w;
        w.x = packh2_acc(w_ih1[(0*H1+j)*NF + 2*ip], w_ih1[(0*H1+j)*NF + 2*ip+1]);
        w.y = packh2_acc(w_ih1[(1*H1+j)*NF + 2*ip], w_ih1[(1*H1+j)*NF + 2*ip+1]);
        w.z = packh2_acc(w_ih1[(2*H1+j)*NF + 2*ip], w_ih1[(2*H1+j)*NF + 2*ip+1]);
        w.w = packh2_acc(w_ih1[(3*H1+j)*NF + 2*ip], w_ih1[(3*H1+j)*NF + 2*ip+1]);
        s_wih1[e] = w;
    }
    for (int e = tid; e < H1 * P1; e += 256) {
        int kp = e % P1, j = e / P1;
        uint4 w;
        w.x = packh2_acc(w_hh1[(0*H1+j)*H1 + 2*kp], w_hh1[(0*H1+j)*H1 + 2*kp+1]);
        w.y = packh2_acc(w_hh1[(1*H1+j)*H1 + 2*kp], w_hh1[(1*H1+j)*H1 + 2*kp+1]);
        w.z = packh2_acc(w_hh1[(2*H1+j)*H1 + 2*kp], w_hh1[(2*H1+j)*H1 + 2*kp+1]);
        w.w = packh2_acc(w_hh1[(3*H1+j)*H1 + 2*kp], w_hh1[(3*H1+j)*H1 + 2*kp+1]);
        s_whh1[e] = w;
    }
    for (int e = tid; e < H2 * P1; e += 256) {
        int kp = e % P1, j = e / P1;
        uint4 w;
        w.x = packh2_acc(w_ih2[(0*H2+j)*H1 + 2*kp], w_ih2[(0*H2+j)*H1 + 2*kp+1]);
        w.y = packh2_acc(w_ih2[(1*H2+j)*H1 + 2*kp], w_ih2[(1*H2+j)*H1 + 2*kp+1]);
        w.z = packh2_acc(w_ih2[(2*H2+j)*H1 + 2*kp], w_ih2[(2*H2+j)*H1 + 2*kp+1]);
        w.w = packh2_acc(w_ih2[(3*H2+j)*H1 + 2*kp], w_ih2[(3*H2+j)*H1 + 2*kp+1]);
        s_wih2[e] = w;
    }
    for (int e = tid; e < H2 * P2; e += 256) {
        int kp = e % P2, j = e / P2;
        uint4 w;
        w.x = packh2_acc(w_hh2[(0*H2+j)*H2 + 2*kp], w_hh2[(0*H2+j)*H2 + 2*kp+1]);
        w.y = packh2_acc(w_hh2[(1*H2+j)*H2 + 2*kp], w_hh2[(1*H2+j)*H2 + 2*kp+1]);
        w.z = packh2_acc(w_hh2[(2*H2+j)*H2 + 2*kp], w_hh2[(2*H2+j)*H2 + 2*kp+1]);
        w.w = packh2_acc(w_hh2[(3*H2+j)*H2 + 2*kp], w_hh2[(3*H2+j)*H2 + 2*kp+1]);
        s_whh2[e] = w;
    }
    {
        float* d = reinterpret_cast<float*>(s_b1);
        if (tid < H1 * 4) {
            int g = tid & 3, j = tid >> 2;
            d[tid] = b_ih1[g * H1 + j] + b_hh1[g * H1 + j];
        }
        d = reinterpret_cast<float*>(s_b2);
        if (tid < H2 * 4) {
            int g = tid & 3, j = tid >> 2;
            d[tid] = b_ih2[g * H2 + j] + b_hh2[g * H2 + j];
        }
    }
    __syncthreads();

    // two batch elements per thread (A,B), both coalesced within the block
    const int base = blockIdx.x * 512;
    const int bA = base + tid;
    const int bB = base + 256 + tid;
    const bool vA = (bA < batch);
    const bool vB = (bB < batch);
    const float* __restrict__ xbA = x + (size_t)(vA ? bA : (batch-1)) * (T * NF);
    const float* __restrict__ xbB = x + (size_t)(vB ? bB : (batch-1)) * (T * NF);

    // state: h packed fp16 pairs (dot2 operands), c fp32 (accuracy)
    uint  h1pA[P1], h1pB[P1], h2pA[P2], h2pB[P2];
    float c1A[H1], c1B[H1], c2A[H2], c2B[H2];
    #pragma unroll
    for (int p = 0; p < P1; ++p) { h1pA[p] = 0u; h1pB[p] = 0u; }
    #pragma unroll
    for (int p = 0; p < P2; ++p) { h2pA[p] = 0u; h2pB[p] = 0u; }
    #pragma unroll
    for (int j = 0; j < H1; ++j) { c1A[j] = 0.f; c1B[j] = 0.f; }
    #pragma unroll
    for (int j = 0; j < H2; ++j) { c2A[j] = 0.f; c2B[j] = 0.f; }

    #pragma unroll 1   // one timestep per scheduling region (proven R1/R3/R4)
    for (int t = 0; t < T; ++t) {
        // ---- load x_t, pack to fp16 pairs ----
        uint xpA[NP], xpB[NP];
        {
            const float2* pa = reinterpret_cast<const float2*>(xbA + t * NF);
            const float2* pb = reinterpret_cast<const float2*>(xbB + t * NF);
            #pragma unroll
            for (int ip = 0; ip < NP; ++ip) {
                float2 a = pa[ip]; xpA[ip] = pkrtz(a.x, a.y);
                float2 b = pb[ip]; xpB[ip] = pkrtz(b.x, b.y);
            }
        }

        // ---- layer 1: rows in pairs ----
        uint h1nA[P1], h1nB[P1];
        #pragma unroll
        for (int jp = 0; jp < P1; ++jp) {
            const int j0 = 2 * jp, j1 = 2 * jp + 1;
            const float4 bv0 = s_b1[j0], bv1 = s_b1[j1];
            float4 aA0 = bv0, aA1 = bv1, aB0 = bv0, aB1 = bv1;
            #pragma unroll
            for (int ip = 0; ip < NP; ++ip) {
                const uint4 w0 = s_wih1[j0 * NP + ip];   // b128 broadcast
                const uint4 w1 = s_wih1[j1 * NP + ip];
                const uint xA = xpA[ip], xB = xpB[ip];
                dot4(aA0, w0, xA);  dot4(aB0, w0, xB);
                dot4(aA1, w1, xA);  dot4(aB1, w1, xB);
            }
            if (t > 0) {   // h1==0 at t==0: recurrent part exactly 0
                #pragma unroll
                for (int kp = 0; kp < P1; ++kp) {
                    const uint4 w0 = s_whh1[j0 * P1 + kp];
                    const uint4 w1 = s_whh1[j1 * P1 + kp];
                    const uint hA = h1pA[kp], hB = h1pB[kp];
                    dot4(aA0, w0, hA);  dot4(aB0, w0, hB);
                    dot4(aA1, w1, hA);  dot4(aB1, w1, hB);
                }
            }
            const float hA0 = cellh(aA0, c1A[j0]);
            const float hA1 = cellh(aA1, c1A[j1]);
            const float hB0 = cellh(aB0, c1B[j0]);
            const float hB1 = cellh(aB1, c1B[j1]);
            h1nA[jp] = pkrtz(hA0, hA1);
            h1nB[jp] = pkrtz(hB0, hB1);
            __builtin_amdgcn_sched_barrier(0);   // bound live set per row-pair
        }
        #pragma unroll
        for (int p = 0; p < P1; ++p) { h1pA[p] = h1nA[p]; h1pB[p] = h1nB[p]; }

        // ---- layer 2: rows in pairs, K over this-t h1 ----
        uint h2nA[P2], h2nB[P2];
        #pragma unroll
        for (int jp = 0; jp < P2; ++jp) {
            const int j0 = 2 * jp, j1 = 2 * jp + 1;
            const float4 bv0 = s_b2[j0], bv1 = s_b2[j1];
            float4 aA0 = bv0, aA1 = bv1, aB0 = bv0, aB1 = bv1;
            #pragma unroll
            for (int kp = 0; kp < P1; ++kp) {
                const uint4 w0 = s_wih2[j0 * P1 + kp];
                const uint4 w1 = s_wih2[j1 * P1 + kp];
                const uint hA = h1pA[kp], hB = h1pB[kp];
                dot4(aA0, w0, hA);  dot4(aB0, w0, hB);
                dot4(aA1, w1, hA);  dot4(aB1, w1, hB);
            }
            if (t > 0) {
                #pragma unroll
                for (int kp = 0; kp < P2; ++kp) {
                    const uint4 w0 = s_whh2[j0 * P2 + kp];
                    const uint4 w1 = s_whh2[j1 * P2 + kp];
                    const uint hA = h2pA[kp], hB = h2pB[kp];
                    dot4(aA0, w0, hA);  dot4(aB0, w0, hB);
                    dot4(aA1, w1, hA);  dot4(aB1, w1, hB);
                }
            }
            const float hA0 = cellh(aA0, c2A[j0]);
            const float hA1 = cellh(aA1, c2A[j1]);
            const float hB0 = cellh(aB0, c2B[j0]);
            const float hB1 = cellh(aB1, c2B[j1]);
            h2nA[jp] = pkrtz(hA0, hA1);
            h2nB[jp] = pkrtz(hB0, hB1);
            __builtin_amdgcn_sched_barrier(0);
        }
        #pragma unroll
        for (int p = 0; p < P2; ++p) { h2pA[p] = h2nA[p]; h2pB[p] = h2nB[p]; }
    }

    // ---- write final h2 (unpack fp16 pairs), 32B per element, coalesced ----
    if (vA) {
        HP p0, p1, p2, p3;
        p0.u = h2pA[0]; p1.u = h2pA[1]; p2.u = h2pA[2]; p3.u = h2pA[3];
        float4* op = reinterpret_cast<float4*>(out + (size_t)bA * H2);
        op[0] = make_float4((float)p0.h[0], (float)p0.h[1], (float)p1.h[0], (float)p1.h[1]);
        op[1] = make_float4((float)p2.h[0], (float)p2.h[1], (float)p3.h[0], (float)p3.h[1]);
    }
    if (vB) {
        HP p0, p1, p2, p3;
        p0.u = h2pB[0]; p1.u = h2pB[1]; p2.u = h2pB[2]; p3.u = h2pB[3];
        float4* op = reinterpret_cast<float4*>(out + (size_t)bB * H2);
        op[0] = make_float4((float)p0.h[0], (float)p0.h[1], (float)p1.h[0], (float)p1.h[1]);
        op[1] = make_float4((float)p2.h[0], (float)p2.h[1], (float)p3.h[0], (float)p3.h[1]);
    }
}

extern "C" void kernel_launch(void* const* d_in, const int* in_sizes, int n_in,
                              void* d_out, int out_size, void* d_ws, size_t ws_size,
                              hipStream_t stream)
{
    const float* x     = (const float*)d_in[0];
    const float* w_ih1 = (const float*)d_in[1];
    const float* w_hh1 = (const float*)d_in[2];
    const float* b_ih1 = (const float*)d_in[3];
    const float* b_hh1 = (const float*)d_in[4];
    const float* w_ih2 = (const float*)d_in[5];
    const float* w_hh2 = (const float*)d_in[6];
    const float* b_ih2 = (const float*)d_in[7];
    const float* b_hh2 = (const float*)d_in[8];
    float* out = (float*)d_out;

    const int batch = in_sizes[0] / (T * NF);
    const int block = 256;
    const int elems_per_block = block * 2;
    const int grid  = (batch + elems_per_block - 1) / elems_per_block;
    lstm2_fused<<<grid, block, 0, stream>>>(x, w_ih1, w_hh1, b_ih1, b_hh1,
                                            w_ih2, w_hh2, b_ih2, b_hh2,
                                            out, batch);
}

// Round 9
// 159.134 us; speedup vs baseline: 2.7940x; 1.4258x over previous
//
#include <hip/hip_runtime.h>

#define DEV_INLINE __device__ __forceinline__

constexpr int NF = 26;   // input features
constexpr int H1 = 24;   // layer-1 hidden
constexpr int H2 = 8;    // layer-2 hidden
constexpr int T  = 5;    // sequence length
constexpr int BPW  = 32; // batch rows per wave (2 M-tiles of 16)
constexpr int ROWU = 20; // uints per LDS row (40 f16 = 80 B: 5x uint4, conflict-free A-frag reads)

typedef _Float16 f16x8 __attribute__((ext_vector_type(8)));
typedef float    f32x4 __attribute__((ext_vector_type(4)));
typedef __fp16   fp16x2 __attribute__((ext_vector_type(2)));

union Q { uint4 u; f16x8 h; };

DEV_INLINE float fast_rcp(float x) { return __builtin_amdgcn_rcpf(x); }
DEV_INLINE float fast_sigmoid(float x) { return fast_rcp(1.0f + __expf(-x)); }
DEV_INLINE float fast_tanh(float x) {
    return fmaf(2.0f, fast_rcp(1.0f + __expf(-2.0f * x)), -1.0f);
}
DEV_INLINE float cellh(float i_, float f_, float g_, float o_, float& c) {
    const float ig = fast_sigmoid(i_), fg = fast_sigmoid(f_);
    const float gg = fast_tanh(g_),    og = fast_sigmoid(o_);
    c = fmaf(fg, c, ig * gg);
    return og * fast_tanh(c);
}
DEV_INLINE uint pkrtz(float a, float b) {
    union { uint u; fp16x2 p; } v; v.p = __builtin_amdgcn_cvt_pkrtz(a, b); return v.u;
}

// One wave = 32 batch rows. Weights held in B-fragments in VGPRs (loaded once).
// Layer-1 N-layout (128 cols): i_j at col j, f_j at 32+j, g_j at 64+j, o_j at 96+j
//   -> all 4 gates of row j in the SAME lane of the C-layout (col = lane&15; m89).
// Layer-2: K-concat [h1(0..23) | h2(24..31)] = K=32; W_hh1 rows 24..31 are zero so
//   the SAME A-fragment (sH rows) serves layer-1 recurrence AND layer-2 input.
// A/B packed with identical (quarter,elem)->k convention: any HW k-permutation
// cancels in the dot product; only the C layout (HW-verified) must be exact.

__global__ __launch_bounds__(256, 2) void lstm2_mfma(
    const float* __restrict__ x,
    const float* __restrict__ w_ih1, const float* __restrict__ w_hh1,
    const float* __restrict__ b_ih1, const float* __restrict__ b_hh1,
    const float* __restrict__ w_ih2, const float* __restrict__ w_hh2,
    const float* __restrict__ b_ih2, const float* __restrict__ b_hh2,
    float* __restrict__ out, int batch)
{
    __shared__ uint sX[4][BPW * ROWU];   // x_t, f16, rows 0..31, cols 0..25 (+pad0)
    __shared__ uint sH[4][BPW * ROWU];   // [h1 | h2] f16, cols 0..23 | 24..31

    const int tid = threadIdx.x;
    const int w   = tid >> 6;        // wave id (LDS region)
    const int l   = tid & 63;        // lane
    const int q   = l >> 4;          // quarter (k-slice 8q..8q+7)
    const int r16 = l & 15;          // row (A) / col (B,C) within tile
    const int wb  = blockIdx.x * 128 + w * BPW;

    // ---- zero LDS (k-pads + h=0 initial state) ----
    for (int i = l; i < BPW * ROWU; i += 64) { sX[w][i] = 0u; sH[w][i] = 0u; }

    // ---- weight B-fragments + biases (registers, once) ----
    f16x8 Bih1[8], Bhh1[8], Bc2[4];
    float bias1[8], bias2[4];
    #pragma unroll
    for (int tau = 0; tau < 8; ++tau) {
        const int gate = tau >> 1, j = (tau & 1) * 16 + r16;
        const bool jv = (j < H1);
        const int row = gate * H1 + (jv ? j : 0);
        f16x8 bi, bh;
        #pragma unroll
        for (int e = 0; e < 8; ++e) {
            const int k = q * 8 + e;
            const float vi = (jv && k < NF) ? w_ih1[row * NF + k] : 0.0f;
            const float vh = (jv && k < H1) ? w_hh1[row * H1 + k] : 0.0f;
            bi[e] = (_Float16)vi; bh[e] = (_Float16)vh;
        }
        Bih1[tau] = bi; Bhh1[tau] = bh;
        bias1[tau] = jv ? (b_ih1[row] + b_hh1[row]) : 0.0f;
    }
    #pragma unroll
    for (int t2 = 0; t2 < 4; ++t2) {
        const int j2 = r16;
        const bool jv = (j2 < H2);
        const int row = t2 * H2 + (jv ? j2 : 0);
        f16x8 bc;
        #pragma unroll
        for (int e = 0; e < 8; ++e) {
            const int k = q * 8 + e;
            float v;
            if (k < H1) v = jv ? w_ih2[row * H1 + k] : 0.0f;        // h1 part
            else        v = jv ? w_hh2[row * H2 + (k - H1)] : 0.0f; // h2 part
            bc[e] = (_Float16)v;
        }
        Bc2[t2] = bc;
        bias2[t2] = jv ? (b_ih2[row] + b_hh2[row]) : 0.0f;
    }

    // ---- x staging assignment: lane covers (row = l&31, half = l>>5) ----
    const int srow = l & 31;
    const int part = l >> 5;                 // 0: pairs 0..6, 1: pairs 7..12
    int grow = wb + srow; if (grow > batch - 1) grow = batch - 1;
    const float* __restrict__ xr = x + (size_t)grow * (T * NF);

    float c1a[2][4] = {}, c1b[2][4] = {}, c2s[2][4] = {}, h2o[2][4];
    const uint4* XQ = reinterpret_cast<const uint4*>(&sX[w][0]);
    const uint4* HQ = reinterpret_cast<const uint4*>(&sH[w][0]);
    _Float16*   Hh  = reinterpret_cast<_Float16*>(&sH[w][0]);

    __syncthreads();   // zeros + prologue visible

    #pragma unroll 1
    for (int t = 0; t < T; ++t) {
        // ---- stage x_t: f32 -> packed f16 pairs into sX rows ----
        {
            const int ip0 = part ? 7 : 0, ipn = part ? 6 : 7;
            #pragma unroll
            for (int ii = 0; ii < 7; ++ii) {
                if (ii < ipn) {
                    const int ip = ip0 + ii;
                    const float2 v = *reinterpret_cast<const float2*>(xr + t * NF + 2 * ip);
                    sX[w][srow * ROWU + ip] = pkrtz(v.x, v.y);
                }
            }
        }
        __syncthreads();   // (A) x visible; prev-t h writes visible
        Q xa[2], ha[2];
        #pragma unroll
        for (int m = 0; m < 2; ++m) {
            xa[m].u = XQ[(m * 16 + r16) * 5 + q];   // A-frag: row r16, k-slice 8q
            ha[m].u = HQ[(m * 16 + r16) * 5 + q];   // [h1|h2] A-frag (prev t)
        }
        __syncthreads();   // (B) frag reads done before h1 overwrites

        // ---- layer 1: per M-tile, 16 MFMA then cell (all-lane, no shuffles) ----
        #pragma unroll
        for (int m = 0; m < 2; ++m) {
            f32x4 acc[8];
            #pragma unroll
            for (int tau = 0; tau < 8; ++tau) {
                const float b = bias1[tau];
                f32x4 bv = {b, b, b, b};
                acc[tau] = bv;
            }
            #pragma unroll
            for (int tau = 0; tau < 8; ++tau) {
                acc[tau] = __builtin_amdgcn_mfma_f32_16x16x32_f16(xa[m].h, Bih1[tau], acc[tau], 0, 0, 0);
                acc[tau] = __builtin_amdgcn_mfma_f32_16x16x32_f16(ha[m].h, Bhh1[tau], acc[tau], 0, 0, 0);
            }
            #pragma unroll
            for (int r = 0; r < 4; ++r) {
                const int lrow = m * 16 + q * 4 + r;      // C row = 4*(l>>4)+reg (m89)
                const float hA = cellh(acc[0][r], acc[2][r], acc[4][r], acc[6][r], c1a[m][r]);
                const float hB = cellh(acc[1][r], acc[3][r], acc[5][r], acc[7][r], c1b[m][r]);
                Hh[lrow * 40 + r16] = (_Float16)hA;                       // j = r16
                if (r16 < 8) Hh[lrow * 40 + 16 + r16] = (_Float16)hB;     // j = 16+r16
            }
        }
        __syncthreads();   // (C) new h1 visible

        // ---- layer 2: A = [h1(t) | h2(t-1)], 4 MFMA per M-tile ----
        Q hc[2];
        #pragma unroll
        for (int m = 0; m < 2; ++m) hc[m].u = HQ[(m * 16 + r16) * 5 + q];
        #pragma unroll
        for (int m = 0; m < 2; ++m) {
            f32x4 a2[4];
            #pragma unroll
            for (int t2 = 0; t2 < 4; ++t2) {
                const float b = bias2[t2];
                f32x4 bv = {b, b, b, b};
                a2[t2] = bv;
            }
            #pragma unroll
            for (int t2 = 0; t2 < 4; ++t2)
                a2[t2] = __builtin_amdgcn_mfma_f32_16x16x32_f16(hc[m].h, Bc2[t2], a2[t2], 0, 0, 0);
            #pragma unroll
            for (int r = 0; r < 4; ++r) {
                const int lrow = m * 16 + q * 4 + r;
                const float h2v = cellh(a2[0][r], a2[1][r], a2[2][r], a2[3][r], c2s[m][r]);
                h2o[m][r] = h2v;
                if (r16 < 8) Hh[lrow * 40 + 24 + r16] = (_Float16)h2v;    // h2 cols 24..31
            }
        }
        // loop: t+1 staging writes only sX; barrier (A) orders h2 writes vs reads
    }

    // ---- output: C-layout rows, col j2 = r16 (<8), f32 coalesced-ish ----
    #pragma unroll
    for (int m = 0; m < 2; ++m) {
        #pragma unroll
        for (int r = 0; r < 4; ++r) {
            const int row = wb + m * 16 + q * 4 + r;
            if (r16 < 8 && row < batch) out[(size_t)row * H2 + r16] = h2o[m][r];
        }
    }
}

extern "C" void kernel_launch(void* const* d_in, const int* in_sizes, int n_in,
                              void* d_out, int out_size, void* d_ws, size_t ws_size,
                              hipStream_t stream)
{
    const float* x     = (const float*)d_in[0];
    const float* w_ih1 = (const float*)d_in[1];
    const float* w_hh1 = (const float*)d_in[2];
    const float* b_ih1 = (const float*)d_in[3];
    const float* b_hh1 = (const float*)d_in[4];
    const float* w_ih2 = (const float*)d_in[5];
    const float* w_hh2 = (const float*)d_in[6];
    const float* b_ih2 = (const float*)d_in[7];
    const float* b_hh2 = (const float*)d_in[8];
    float* out = (float*)d_out;

    const int batch = in_sizes[0] / (T * NF);
    const int block = 256;                    // 4 waves x 32 batch rows
    const int grid  = (batch + 127) / 128;
    lstm2_mfma<<<grid, block, 0, stream>>>(x, w_ih1, w_hh1, b_ih1, b_hh1,
                                           w_ih2, w_hh2, b_ih2, b_hh2,
                                           out, batch);
}

// Round 10
// 150.288 us; speedup vs baseline: 2.9584x; 1.0589x over previous
//
#include <hip/hip_runtime.h>

#define DEV_INLINE __device__ __forceinline__

constexpr int NF = 26;   // input features
constexpr int H1 = 24;   // layer-1 hidden
constexpr int H2 = 8;    // layer-2 hidden
constexpr int T  = 5;    // sequence length
constexpr int BPW  = 32; // batch rows per wave (2 M-tiles of 16)
constexpr int ROWU = 20; // uints per LDS row (40 f16 = 80 B -> 2-way-max bank aliasing on b128)

typedef _Float16 f16x8 __attribute__((ext_vector_type(8)));
typedef float    f32x4 __attribute__((ext_vector_type(4)));
typedef __fp16   fp16x2 __attribute__((ext_vector_type(2)));

union Q { uint4 u; f16x8 h; };

DEV_INLINE float fast_rcp(float x) { return __builtin_amdgcn_rcpf(x); }
DEV_INLINE float fast_sigmoid(float x) { return fast_rcp(1.0f + __expf(-x)); }
DEV_INLINE float fast_tanh(float x) {
    return fmaf(2.0f, fast_rcp(1.0f + __expf(-2.0f * x)), -1.0f);
}
DEV_INLINE float cellh(float i_, float f_, float g_, float o_, float& c) {
    const float ig = fast_sigmoid(i_), fg = fast_sigmoid(f_);
    const float gg = fast_tanh(g_),    og = fast_sigmoid(o_);
    c = fmaf(fg, c, ig * gg);
    return og * fast_tanh(c);
}
DEV_INLINE uint pkrtz(float a, float b) {
    union { uint u; fp16x2 p; } v; v.p = __builtin_amdgcn_cvt_pkrtz(a, b); return v.u;
}

// R10: NO __syncthreads anywhere. sH is wave-private; DS ops from one wave
// complete in order, so ordering needs only a compiler fence (sched_barrier(0),
// zero cycles). x is loaded DIRECTLY in A-fragment layout from global (float2,
// 8B-aligned), 1-deep prefetch rotation hides HBM latency under compute.
// Weights in B-fragments in VGPRs (loaded once); layer-1 N=128 gate-major
// columns put all 4 gates of row j in one lane (C layout m89); layer-2 K-concat
// [h1|h2]=32 reuses one A-fragment for L1-recurrence and L2-input.

__global__ __launch_bounds__(256, 2) void lstm2_mfma(
    const float* __restrict__ x,
    const float* __restrict__ w_ih1, const float* __restrict__ w_hh1,
    const float* __restrict__ b_ih1, const float* __restrict__ b_hh1,
    const float* __restrict__ w_ih2, const float* __restrict__ w_hh2,
    const float* __restrict__ b_ih2, const float* __restrict__ b_hh2,
    float* __restrict__ out, int batch)
{
    __shared__ uint sH[4][BPW * ROWU];   // [h1 cols 0..23 | h2 cols 24..31] f16, per-wave

    const int tid = threadIdx.x;
    const int w   = tid >> 6;        // wave id (private LDS region)
    const int l   = tid & 63;        // lane
    const int q   = l >> 4;          // quarter (k-slice 8q..8q+7)
    const int r16 = l & 15;          // row (A) / col (B,C) within 16x16 tile
    const int wb  = blockIdx.x * 128 + w * BPW;

    // ---- zero sH (h=0 init); wave-private -> no barrier ----
    for (int i = l; i < BPW * ROWU; i += 64) sH[w][i] = 0u;

    // ---- weight B-fragments + biases (registers, once) ----
    f16x8 Bih1[8], Bhh1[8], Bc2[4];
    float bias1[8], bias2[4];
    #pragma unroll
    for (int tau = 0; tau < 8; ++tau) {
        const int gate = tau >> 1, j = (tau & 1) * 16 + r16;
        const bool jv = (j < H1);
        const int row = gate * H1 + (jv ? j : 0);
        f16x8 bi, bh;
        #pragma unroll
        for (int e = 0; e < 8; ++e) {
            const int k = q * 8 + e;
            const float vi = (jv && k < NF) ? w_ih1[row * NF + k] : 0.0f;
            const float vh = (jv && k < H1) ? w_hh1[row * H1 + k] : 0.0f;
            bi[e] = (_Float16)vi; bh[e] = (_Float16)vh;
        }
        Bih1[tau] = bi; Bhh1[tau] = bh;
        bias1[tau] = jv ? (b_ih1[row] + b_hh1[row]) : 0.0f;
    }
    #pragma unroll
    for (int t2 = 0; t2 < 4; ++t2) {
        const int j2 = r16;
        const bool jv = (j2 < H2);
        const int row = t2 * H2 + (jv ? j2 : 0);
        f16x8 bc;
        #pragma unroll
        for (int e = 0; e < 8; ++e) {
            const int k = q * 8 + e;
            float v;
            if (k < H1) v = jv ? w_ih2[row * H1 + k] : 0.0f;        // h1 part
            else        v = jv ? w_hh2[row * H2 + (k - H1)] : 0.0f; // h2 part
            bc[e] = (_Float16)v;
        }
        Bc2[t2] = bc;
        bias2[t2] = jv ? (b_ih2[row] + b_hh2[row]) : 0.0f;
    }

    // ---- x: direct A-fragment loads. lane (q,r16) of tile m reads
    //      row wb+m*16+r16, floats k=q*8..q*8+7 (q==3: only k=24,25; rest 0) ----
    int row0 = wb + r16;      if (row0 > batch - 1) row0 = batch - 1;
    int row1 = wb + 16 + r16; if (row1 > batch - 1) row1 = batch - 1;
    const float* __restrict__ xp0 = x + (size_t)row0 * (T * NF) + q * 8;
    const float* __restrict__ xp1 = x + (size_t)row1 * (T * NF) + q * 8;
    const bool q3 = (q == 3);
    const float2 z2 = make_float2(0.0f, 0.0f);

    float2 xr_[2][4];   // raw f32 pairs of timestep being computed (static idx only)
    #pragma unroll
    for (int m = 0; m < 2; ++m) {
        const float* __restrict__ p = m ? xp1 : xp0;
        xr_[m][0] = *reinterpret_cast<const float2*>(p);
        xr_[m][1] = q3 ? z2 : *reinterpret_cast<const float2*>(p + 2);
        xr_[m][2] = q3 ? z2 : *reinterpret_cast<const float2*>(p + 4);
        xr_[m][3] = q3 ? z2 : *reinterpret_cast<const float2*>(p + 6);
    }

    float c1a[2][4] = {}, c1b[2][4] = {}, c2s[2][4] = {}, h2o[2][4];
    const uint4* HQ = reinterpret_cast<const uint4*>(&sH[w][0]);
    _Float16*   Hh  = reinterpret_cast<_Float16*>(&sH[w][0]);

    #pragma unroll 1
    for (int t = 0; t < T; ++t) {
        // ---- convert current raws -> A-frags (q3 lanes: pairs 1..3 are zero) ----
        Q xa[2];
        #pragma unroll
        for (int m = 0; m < 2; ++m) {
            uint4 u;
            u.x = pkrtz(xr_[m][0].x, xr_[m][0].y);
            u.y = pkrtz(xr_[m][1].x, xr_[m][1].y);
            u.z = pkrtz(xr_[m][2].x, xr_[m][2].y);
            u.w = pkrtz(xr_[m][3].x, xr_[m][3].y);
            xa[m].u = u;
        }
        // ---- prefetch t+1 raws (consumed next iteration; latency hides under t) ----
        if (t < T - 1) {
            #pragma unroll
            for (int m = 0; m < 2; ++m) {
                const float* __restrict__ p = (m ? xp1 : xp0) + (t + 1) * NF;
                xr_[m][0] = *reinterpret_cast<const float2*>(p);
                xr_[m][1] = q3 ? z2 : *reinterpret_cast<const float2*>(p + 2);
                xr_[m][2] = q3 ? z2 : *reinterpret_cast<const float2*>(p + 4);
                xr_[m][3] = q3 ? z2 : *reinterpret_cast<const float2*>(p + 6);
            }
        }

        // ---- read [h1|h2](prev t) A-frags; in-order DS pipe, wave-private ----
        Q ha[2];
        #pragma unroll
        for (int m = 0; m < 2; ++m) ha[m].u = HQ[(m * 16 + r16) * 5 + q];
        __builtin_amdgcn_sched_barrier(0);   // frag reads before h1 overwrite (WAR)

        // ---- layer 1: 16 MFMA per M-tile, then cells (no cross-lane) ----
        #pragma unroll
        for (int m = 0; m < 2; ++m) {
            f32x4 acc[8];
            #pragma unroll
            for (int tau = 0; tau < 8; ++tau) {
                const float b = bias1[tau];
                f32x4 bv = {b, b, b, b};
                acc[tau] = bv;
            }
            #pragma unroll
            for (int tau = 0; tau < 8; ++tau) {
                acc[tau] = __builtin_amdgcn_mfma_f32_16x16x32_f16(xa[m].h, Bih1[tau], acc[tau], 0, 0, 0);
                acc[tau] = __builtin_amdgcn_mfma_f32_16x16x32_f16(ha[m].h, Bhh1[tau], acc[tau], 0, 0, 0);
            }
            #pragma unroll
            for (int r = 0; r < 4; ++r) {
                const int lrow = m * 16 + q * 4 + r;      // C row = 4*(l>>4)+reg (m89)
                const float hA = cellh(acc[0][r], acc[2][r], acc[4][r], acc[6][r], c1a[m][r]);
                const float hB = cellh(acc[1][r], acc[3][r], acc[5][r], acc[7][r], c1b[m][r]);
                Hh[lrow * 40 + r16] = (_Float16)hA;                   // j = r16
                if (r16 < 8) Hh[lrow * 40 + 16 + r16] = (_Float16)hB; // j = 16+r16
            }
        }
        __builtin_amdgcn_sched_barrier(0);   // h1 writes before hc reads (RAW)

        // ---- layer 2: A = [h1(t) | h2(t-1)], 4 MFMA per M-tile ----
        Q hc[2];
        #pragma unroll
        for (int m = 0; m < 2; ++m) hc[m].u = HQ[(m * 16 + r16) * 5 + q];
        __builtin_amdgcn_sched_barrier(0);   // hc reads before h2 overwrite (WAR)
        #pragma unroll
        for (int m = 0; m < 2; ++m) {
            f32x4 a2[4];
            #pragma unroll
            for (int t2 = 0; t2 < 4; ++t2) {
                const float b = bias2[t2];
                f32x4 bv = {b, b, b, b};
                a2[t2] = bv;
            }
            #pragma unroll
            for (int t2 = 0; t2 < 4; ++t2)
                a2[t2] = __builtin_amdgcn_mfma_f32_16x16x32_f16(hc[m].h, Bc2[t2], a2[t2], 0, 0, 0);
            #pragma unroll
            for (int r = 0; r < 4; ++r) {
                const int lrow = m * 16 + q * 4 + r;
                const float h2v = cellh(a2[0][r], a2[1][r], a2[2][r], a2[3][r], c2s[m][r]);
                h2o[m][r] = h2v;
                if (r16 < 8) Hh[lrow * 40 + 24 + r16] = (_Float16)h2v; // h2 cols 24..31
            }
        }
        __builtin_amdgcn_sched_barrier(0);   // h2 writes before next-t ha reads (RAW)
    }

    // ---- output: row = wb + m*16 + q*4 + r, col = r16 (<8), f32 ----
    #pragma unroll
    for (int m = 0; m < 2; ++m) {
        #pragma unroll
        for (int r = 0; r < 4; ++r) {
            const int row = wb + m * 16 + q * 4 + r;
            if (r16 < 8 && row < batch) out[(size_t)row * H2 + r16] = h2o[m][r];
        }
    }
}

extern "C" void kernel_launch(void* const* d_in, const int* in_sizes, int n_in,
                              void* d_out, int out_size, void* d_ws, size_t ws_size,
                              hipStream_t stream)
{
    const float* x     = (const float*)d_in[0];
    const float* w_ih1 = (const float*)d_in[1];
    const float* w_hh1 = (const float*)d_in[2];
    const float* b_ih1 = (const float*)d_in[3];
    const float* b_hh1 = (const float*)d_in[4];
    const float* w_ih2 = (const float*)d_in[5];
    const float* w_hh2 = (const float*)d_in[6];
    const float* b_ih2 = (const float*)d_in[7];
    const float* b_hh2 = (const float*)d_in[8];
    float* out = (float*)d_out;

    const int batch = in_sizes[0] / (T * NF);
    const int block = 256;                    // 4 independent waves x 32 batch rows
    const int grid  = (batch + 127) / 128;
    lstm2_mfma<<<grid, block, 0, stream>>>(x, w_ih1, w_hh1, b_ih1, b_hh1,
                                           w_ih2, w_hh2, b_ih2, b_hh2,
                                           out, batch);
}